// Round 2
// baseline (38.788 us; speedup 1.0000x reference)
//
#include <hip/hip_runtime.h>
#include <math.h>

#define WH 65536   // 256*256
#define NK 68

__device__ __forceinline__ float4 aff4(float4 f0, float4 f1, float4 f2,
                                       float r0, float r1, float r2, float t) {
    float4 y;
    y.x = fmaf(f0.x, r0, fmaf(f1.x, r1, fmaf(f2.x, r2, t)));
    y.y = fmaf(f0.y, r0, fmaf(f1.y, r1, fmaf(f2.y, r2, t)));
    y.z = fmaf(f0.z, r0, fmaf(f1.z, r1, fmaf(f2.z, r2, t)));
    y.w = fmaf(f0.w, r0, fmaf(f1.w, r1, fmaf(f2.w, r2, t)));
    return y;
}

// One fused kernel: every block redundantly solves its batch's Procrustes
// (wave 0 only; inputs ~3.5KB/batch, L2-hot) while all waves' streaming
// float4 loads are in flight, then applies the affine.
__global__ __launch_bounds__(256, 4) void fused_kernel(
    const float* __restrict__ Off, const float* __restrict__ P,
    const float* __restrict__ att, const float* __restrict__ meanp,
    const int* __restrict__ uv, float* __restrict__ out)
{
    const int b = blockIdx.y;
    const int t = threadIdx.x;
    __shared__ float sRT[12];

    // ---- issue streaming loads first (all waves) ----
    const size_t p = ((size_t)blockIdx.x * 256 + t) * 4;
    const float* ob = Off + (size_t)b * 3 * WH;
    const float4 o0 = *(const float4*)(ob + 0*WH + p);
    const float4 o1 = *(const float4*)(ob + 1*WH + p);
    const float4 o2 = *(const float4*)(ob + 2*WH + p);
    const float4 m0 = *(const float4*)(meanp + 0*WH + p);
    const float4 m1 = *(const float4*)(meanp + 1*WH + p);
    const float4 m2 = *(const float4*)(meanp + 2*WH + p);

    // ---- wave 0: per-batch Procrustes solve ----
    if (t < 64) {
        const float* Pb = P  + (size_t)b * 3 * WH;
        const float* attb = att + (size_t)b * 35 * 35;

        float src[2][3], dst[2][3], wgt[2];
        #pragma unroll
        for (int i = 0; i < 2; ++i) {
            const int k = t + 64 * i;
            const bool act = (k < NK);
            float p0=0,p1=0,p2=0,s0=0,s1=0,s2=0,w=0;
            if (act) {
                const int u0 = uv[2*k], u1 = uv[2*k+1];
                const int base = u0 * 256 + u1;
                p0 = Pb[0*WH + base];
                p1 = Pb[1*WH + base];
                p2 = Pb[2*WH + base];
                s0 = fmaf(Off[(size_t)b*3*WH + 0*WH + base], 6.0f, meanp[0*WH + base]);
                s1 = fmaf(Off[(size_t)b*3*WH + 1*WH + base], 6.0f, meanp[1*WH + base]);
                s2 = fmaf(Off[(size_t)b*3*WH + 2*WH + base], 6.0f, meanp[2*WH + base]);
                const float r0 = (u0 > 0) ? Pb[0*WH + base - 256] : 0.0f;
                const float r1 = (u0 > 0) ? Pb[1*WH + base - 256] : 0.0f;
                const float d0 = (u1 > 0) ? Pb[0*WH + base - 1]   : 0.0f;
                const float d1v= (u1 > 0) ? Pb[1*WH + base - 1]   : 0.0f;
                const float z = (p0 - r0) * (d1v - r1) - (p1 - r1) * (d0 - r0);
                const float vis = (z > 0.0f) ? 1.0f : ((z < 0.0f) ? 0.1f : z);
                int ix = (int)(p0 * 280.0f) / 8;
                int iy = (int)(p1 * 280.0f) / 8;
                ix = min(max(ix, 0), 34);
                iy = min(max(iy, 0), 34);
                w = vis * attb[iy * 35 + ix];
            }
            dst[i][0]=p0; dst[i][1]=p1; dst[i][2]=p2;
            src[i][0]=s0; src[i][1]=s1; src[i][2]=s2;
            wgt[i]=w;
        }

        float s33[3], d33[3];
        #pragma unroll
        for (int c = 0; c < 3; ++c) {
            s33[c] = __shfl(src[0][c], 33);
            d33[c] = __shfl(dst[0][c], 33);
        }

        float sums[8];
        #pragma unroll
        for (int j = 0; j < 8; ++j) sums[j] = 0.0f;
        #pragma unroll
        for (int i = 0; i < 2; ++i) {
            const bool act = (t + 64*i < NK);
            if (!act) continue;
            #pragma unroll
            for (int c = 0; c < 3; ++c) { sums[c] += src[i][c]; sums[3+c] += dst[i][c]; }
            const float dx0=src[i][0]-s33[0], dx1=src[i][1]-s33[1], dx2=src[i][2]-s33[2];
            const float dy0=dst[i][0]-d33[0], dy1=dst[i][1]-d33[1], dy2=dst[i][2]-d33[2];
            sums[6] += sqrtf(dx0*dx0 + dx1*dx1 + dx2*dx2);
            sums[7] += sqrtf(dy0*dy0 + dy1*dy1 + dy2*dy2);
        }
        #pragma unroll
        for (int m = 1; m < 64; m <<= 1)
            #pragma unroll
            for (int j = 0; j < 8; ++j) sums[j] += __shfl_xor(sums[j], m);

        const float inv_nk = 1.0f / (float)NK;
        const float ms0 = sums[0]*inv_nk, ms1 = sums[1]*inv_nk, ms2 = sums[2]*inv_nk;
        const float md0 = sums[3]*inv_nk, md1 = sums[4]*inv_nk, md2 = sums[5]*inv_nk;
        const float s = sums[7] * __builtin_amdgcn_rcpf(sums[6]);   // d2/d1

        float M[9];
        #pragma unroll
        for (int j = 0; j < 9; ++j) M[j] = 0.0f;
        #pragma unroll
        for (int i = 0; i < 2; ++i) {
            const float a0=src[i][0]-ms0, a1=src[i][1]-ms1, a2=src[i][2]-ms2;
            const float b0=dst[i][0]-md0, b1=dst[i][1]-md1, b2=dst[i][2]-md2;
            const float w = wgt[i];
            M[0]=fmaf(w*a0,b0,M[0]); M[1]=fmaf(w*a0,b1,M[1]); M[2]=fmaf(w*a0,b2,M[2]);
            M[3]=fmaf(w*a1,b0,M[3]); M[4]=fmaf(w*a1,b1,M[4]); M[5]=fmaf(w*a1,b2,M[5]);
            M[6]=fmaf(w*a2,b0,M[6]); M[7]=fmaf(w*a2,b1,M[7]); M[8]=fmaf(w*a2,b2,M[8]);
        }
        #pragma unroll
        for (int m = 1; m < 64; m <<= 1)
            #pragma unroll
            for (int j = 0; j < 9; ++j) M[j] += __shfl_xor(M[j], m);

        if (t == 0) {
            // polar(M^T) via det-scaled Newton; R = V U^T of SVD(M)
            float X[9];
            float fn = 1e-30f;
            #pragma unroll
            for (int e = 0; e < 9; ++e) fn += M[e]*M[e];
            const float rfn = __builtin_amdgcn_rcpf(sqrtf(fn));
            #pragma unroll
            for (int r = 0; r < 3; ++r)
                #pragma unroll
                for (int c = 0; c < 3; ++c)
                    X[r*3+c] = M[c*3+r] * rfn;   // X = M^T / ||M||_F
            #pragma unroll
            for (int it = 0; it < 8; ++it) {
                const float C0 = X[4]*X[8]-X[5]*X[7];
                const float C1 = X[5]*X[6]-X[3]*X[8];
                const float C2 = X[3]*X[7]-X[4]*X[6];
                const float C3 = X[2]*X[7]-X[1]*X[8];
                const float C4 = X[0]*X[8]-X[2]*X[6];
                const float C5 = X[1]*X[6]-X[0]*X[7];
                const float C6 = X[1]*X[5]-X[2]*X[4];
                const float C7 = X[2]*X[3]-X[0]*X[5];
                const float C8 = X[0]*X[4]-X[1]*X[3];
                float det = X[0]*C0 + X[1]*C1 + X[2]*C2;
                if (fabsf(det) < 1e-30f) det = (det < 0.0f) ? -1e-30f : 1e-30f;
                const float ad  = fabsf(det);
                const float g   = exp2f(-0.333333333f * log2f(ad));  // |det|^(-1/3)
                const float idg = __builtin_amdgcn_rcpf(det * g);
                X[0]=0.5f*(g*X[0]+C0*idg); X[1]=0.5f*(g*X[1]+C1*idg); X[2]=0.5f*(g*X[2]+C2*idg);
                X[3]=0.5f*(g*X[3]+C3*idg); X[4]=0.5f*(g*X[4]+C4*idg); X[5]=0.5f*(g*X[5]+C5*idg);
                X[6]=0.5f*(g*X[6]+C6*idg); X[7]=0.5f*(g*X[7]+C7*idg); X[8]=0.5f*(g*X[8]+C8*idg);
            }
            #pragma unroll
            for (int e = 0; e < 9; ++e) sRT[e] = s * X[e];   // Rs
            const float msv[3] = {ms0, ms1, ms2};
            #pragma unroll
            for (int c = 0; c < 3; ++c) {
                float acc = 0.0f;
                #pragma unroll
                for (int j = 0; j < 3; ++j) acc = fmaf(msv[j], X[c*3+j], acc);
                const float mdv = (c==0) ? md0 : ((c==1) ? md1 : md2);
                sRT[9+c] = mdv - s * acc;                    // T
            }
        }
    }

    // ---- compute f = 6*Off + mean while solve finishes ----
    float4 f0, f1, f2;
    f0.x=fmaf(o0.x,6.0f,m0.x); f0.y=fmaf(o0.y,6.0f,m0.y); f0.z=fmaf(o0.z,6.0f,m0.z); f0.w=fmaf(o0.w,6.0f,m0.w);
    f1.x=fmaf(o1.x,6.0f,m1.x); f1.y=fmaf(o1.y,6.0f,m1.y); f1.z=fmaf(o1.z,6.0f,m1.z); f1.w=fmaf(o1.w,6.0f,m1.w);
    f2.x=fmaf(o2.x,6.0f,m2.x); f2.y=fmaf(o2.y,6.0f,m2.y); f2.z=fmaf(o2.z,6.0f,m2.z); f2.w=fmaf(o2.w,6.0f,m2.w);

    __syncthreads();

    const float r00=sRT[0], r01=sRT[1], r02=sRT[2];
    const float r10=sRT[3], r11=sRT[4], r12=sRT[5];
    const float r20=sRT[6], r21=sRT[7], r22=sRT[8];
    const float t0=sRT[9], t1=sRT[10], t2=sRT[11];

    float* outb = out + (size_t)b * 3 * WH;
    *(float4*)(outb + 0*WH + p) = aff4(f0, f1, f2, r00, r01, r02, t0);
    *(float4*)(outb + 1*WH + p) = aff4(f0, f1, f2, r10, r11, r12, t1);
    *(float4*)(outb + 2*WH + p) = aff4(f0, f1, f2, r20, r21, r22, t2);
}

extern "C" void kernel_launch(void* const* d_in, const int* in_sizes, int n_in,
                              void* d_out, int out_size, void* d_ws, size_t ws_size,
                              hipStream_t stream) {
    const float* Off   = (const float*)d_in[0];
    const float* P     = (const float*)d_in[1];
    const float* att   = (const float*)d_in[2];
    const float* meanp = (const float*)d_in[3];
    const int*   uv    = (const int*)d_in[4];
    float* out = (float*)d_out;

    const int B = in_sizes[0] / (3 * WH);
    dim3 grid(WH / (256 * 4), B);
    fused_kernel<<<grid, 256, 0, stream>>>(Off, P, att, meanp, uv, out);
}

// Round 4
// 27.755 us; speedup vs baseline: 1.3975x; 1.3975x over previous
//
#include <hip/hip_runtime.h>
#include <math.h>

#define WH 65536   // 256*256
#define NK 68

typedef float fvec4 __attribute__((ext_vector_type(4)));

// ---------------- Kernel 1: per-batch Procrustes solve ----------------
__global__ __launch_bounds__(64) void solve_kernel(
    const float* __restrict__ Off, const float* __restrict__ P,
    const float* __restrict__ att, const float* __restrict__ meanp,
    const int* __restrict__ uv, float* __restrict__ RT)
{
    const int b = blockIdx.x;
    const int t = threadIdx.x;
    const float* Pb = P  + (size_t)b * 3 * WH;
    const float* Ob = Off + (size_t)b * 3 * WH;
    const float* attb = att + (size_t)b * 35 * 35;

    float src[2][3], dst[2][3], wgt[2];
    #pragma unroll
    for (int i = 0; i < 2; ++i) {
        const int k = t + 64 * i;
        const bool act = (k < NK);
        float p0=0,p1=0,p2=0,s0=0,s1=0,s2=0,w=0;
        if (act) {
            const int u0 = uv[2*k], u1 = uv[2*k+1];
            const int base = u0 * 256 + u1;
            p0 = Pb[0*WH + base];
            p1 = Pb[1*WH + base];
            p2 = Pb[2*WH + base];
            s0 = fmaf(Ob[0*WH + base], 6.0f, meanp[0*WH + base]);
            s1 = fmaf(Ob[1*WH + base], 6.0f, meanp[1*WH + base]);
            s2 = fmaf(Ob[2*WH + base], 6.0f, meanp[2*WH + base]);
            const float r0 = (u0 > 0) ? Pb[0*WH + base - 256] : 0.0f;
            const float r1 = (u0 > 0) ? Pb[1*WH + base - 256] : 0.0f;
            const float d0 = (u1 > 0) ? Pb[0*WH + base - 1]   : 0.0f;
            const float d1v= (u1 > 0) ? Pb[1*WH + base - 1]   : 0.0f;
            const float z = (p0 - r0) * (d1v - r1) - (p1 - r1) * (d0 - r0);
            const float vis = (z > 0.0f) ? 1.0f : ((z < 0.0f) ? 0.1f : z);
            int ix = (int)(p0 * 280.0f) / 8;
            int iy = (int)(p1 * 280.0f) / 8;
            ix = min(max(ix, 0), 34);
            iy = min(max(iy, 0), 34);
            w = vis * attb[iy * 35 + ix];
        }
        dst[i][0]=p0; dst[i][1]=p1; dst[i][2]=p2;
        src[i][0]=s0; src[i][1]=s1; src[i][2]=s2;
        wgt[i]=w;
    }

    float s33[3], d33[3];
    #pragma unroll
    for (int c = 0; c < 3; ++c) {
        s33[c] = __shfl(src[0][c], 33);
        d33[c] = __shfl(dst[0][c], 33);
    }

    float sums[8];
    #pragma unroll
    for (int j = 0; j < 8; ++j) sums[j] = 0.0f;
    #pragma unroll
    for (int i = 0; i < 2; ++i) {
        const bool act = (t + 64*i < NK);
        if (!act) continue;
        #pragma unroll
        for (int c = 0; c < 3; ++c) { sums[c] += src[i][c]; sums[3+c] += dst[i][c]; }
        const float dx0=src[i][0]-s33[0], dx1=src[i][1]-s33[1], dx2=src[i][2]-s33[2];
        const float dy0=dst[i][0]-d33[0], dy1=dst[i][1]-d33[1], dy2=dst[i][2]-d33[2];
        sums[6] += sqrtf(dx0*dx0 + dx1*dx1 + dx2*dx2);
        sums[7] += sqrtf(dy0*dy0 + dy1*dy1 + dy2*dy2);
    }
    #pragma unroll
    for (int m = 1; m < 64; m <<= 1)
        #pragma unroll
        for (int j = 0; j < 8; ++j) sums[j] += __shfl_xor(sums[j], m);

    const float inv_nk = 1.0f / (float)NK;
    const float ms0 = sums[0]*inv_nk, ms1 = sums[1]*inv_nk, ms2 = sums[2]*inv_nk;
    const float md0 = sums[3]*inv_nk, md1 = sums[4]*inv_nk, md2 = sums[5]*inv_nk;
    const float s = sums[7] / sums[6];   // d2/d1

    float M[9];
    #pragma unroll
    for (int j = 0; j < 9; ++j) M[j] = 0.0f;
    #pragma unroll
    for (int i = 0; i < 2; ++i) {
        const float a0=src[i][0]-ms0, a1=src[i][1]-ms1, a2=src[i][2]-ms2;
        const float b0=dst[i][0]-md0, b1=dst[i][1]-md1, b2=dst[i][2]-md2;
        const float w = wgt[i];
        M[0]=fmaf(w*a0,b0,M[0]); M[1]=fmaf(w*a0,b1,M[1]); M[2]=fmaf(w*a0,b2,M[2]);
        M[3]=fmaf(w*a1,b0,M[3]); M[4]=fmaf(w*a1,b1,M[4]); M[5]=fmaf(w*a1,b2,M[5]);
        M[6]=fmaf(w*a2,b0,M[6]); M[7]=fmaf(w*a2,b1,M[7]); M[8]=fmaf(w*a2,b2,M[8]);
    }
    #pragma unroll
    for (int m = 1; m < 64; m <<= 1)
        #pragma unroll
        for (int j = 0; j < 9; ++j) M[j] += __shfl_xor(M[j], m);

    // All lanes hold M; every lane runs the identical polar Newton.
    float X[9];
    float fn = 1e-30f;
    #pragma unroll
    for (int e = 0; e < 9; ++e) fn += M[e]*M[e];
    const float rfn = 1.0f / sqrtf(fn);
    #pragma unroll
    for (int r = 0; r < 3; ++r)
        #pragma unroll
        for (int c = 0; c < 3; ++c)
            X[r*3+c] = M[c*3+r] * rfn;   // X = M^T / ||M||_F
    #pragma unroll
    for (int it = 0; it < 9; ++it) {
        const float C0 = X[4]*X[8]-X[5]*X[7];
        const float C1 = X[5]*X[6]-X[3]*X[8];
        const float C2 = X[3]*X[7]-X[4]*X[6];
        const float C3 = X[2]*X[7]-X[1]*X[8];
        const float C4 = X[0]*X[8]-X[2]*X[6];
        const float C5 = X[1]*X[6]-X[0]*X[7];
        const float C6 = X[1]*X[5]-X[2]*X[4];
        const float C7 = X[2]*X[3]-X[0]*X[5];
        const float C8 = X[0]*X[4]-X[1]*X[3];
        float det = X[0]*C0 + X[1]*C1 + X[2]*C2;
        if (fabsf(det) < 1e-30f) det = (det < 0.0f) ? -1e-30f : 1e-30f;
        const float g   = exp2f(-0.333333333f * log2f(fabsf(det)));  // |det|^(-1/3)
        const float idg = 1.0f / (det * g);
        X[0]=0.5f*(g*X[0]+C0*idg); X[1]=0.5f*(g*X[1]+C1*idg); X[2]=0.5f*(g*X[2]+C2*idg);
        X[3]=0.5f*(g*X[3]+C3*idg); X[4]=0.5f*(g*X[4]+C4*idg); X[5]=0.5f*(g*X[5]+C5*idg);
        X[6]=0.5f*(g*X[6]+C6*idg); X[7]=0.5f*(g*X[7]+C7*idg); X[8]=0.5f*(g*X[8]+C8*idg);
    }
    if (t == 0) {
        float* o = RT + (size_t)b * 12;
        #pragma unroll
        for (int e = 0; e < 9; ++e) o[e] = s * X[e];   // Rs
        const float msv[3] = {ms0, ms1, ms2};
        #pragma unroll
        for (int c = 0; c < 3; ++c) {
            float acc = 0.0f;
            #pragma unroll
            for (int j = 0; j < 3; ++j) acc = fmaf(msv[j], X[c*3+j], acc);
            const float mdv = (c==0) ? md0 : ((c==1) ? md1 : md2);
            o[9+c] = mdv - s * acc;                    // T
        }
    }
}

// ---------------- Kernel 2: fused scale + affine + transpose ----------------
__device__ __forceinline__ fvec4 aff4(fvec4 f0, fvec4 f1, fvec4 f2,
                                      float r0, float r1, float r2, float t) {
    fvec4 y;
    y.x = fmaf(f0.x, r0, fmaf(f1.x, r1, fmaf(f2.x, r2, t)));
    y.y = fmaf(f0.y, r0, fmaf(f1.y, r1, fmaf(f2.y, r2, t)));
    y.z = fmaf(f0.z, r0, fmaf(f1.z, r1, fmaf(f2.z, r2, t)));
    y.w = fmaf(f0.w, r0, fmaf(f1.w, r1, fmaf(f2.w, r2, t)));
    return y;
}

__global__ __launch_bounds__(256) void apply_kernel(
    const float* __restrict__ Off, const float* __restrict__ meanp,
    const float* __restrict__ RT, float* __restrict__ out)
{
    const int b = blockIdx.y;
    const size_t p = ((size_t)blockIdx.x * 256 + threadIdx.x) * 4;
    const float* rt = RT + (size_t)b * 12;
    const float r00=rt[0], r01=rt[1], r02=rt[2];
    const float r10=rt[3], r11=rt[4], r12=rt[5];
    const float r20=rt[6], r21=rt[7], r22=rt[8];
    const float t0=rt[9], t1=rt[10], t2=rt[11];

    // Offset: streaming, zero reuse -> non-temporal loads.
    const float* ob = Off + (size_t)b * 3 * WH;
    const fvec4 o0 = __builtin_nontemporal_load((const fvec4*)(ob + 0*WH + p));
    const fvec4 o1 = __builtin_nontemporal_load((const fvec4*)(ob + 1*WH + p));
    const fvec4 o2 = __builtin_nontemporal_load((const fvec4*)(ob + 2*WH + p));
    // mean: re-read by all 64 batches -> keep cached path (L2/L3-resident).
    const fvec4 m0 = *(const fvec4*)(meanp + 0*WH + p);
    const fvec4 m1 = *(const fvec4*)(meanp + 1*WH + p);
    const fvec4 m2 = *(const fvec4*)(meanp + 2*WH + p);

    fvec4 f0, f1, f2;
    f0.x=fmaf(o0.x,6.0f,m0.x); f0.y=fmaf(o0.y,6.0f,m0.y); f0.z=fmaf(o0.z,6.0f,m0.z); f0.w=fmaf(o0.w,6.0f,m0.w);
    f1.x=fmaf(o1.x,6.0f,m1.x); f1.y=fmaf(o1.y,6.0f,m1.y); f1.z=fmaf(o1.z,6.0f,m1.z); f1.w=fmaf(o1.w,6.0f,m1.w);
    f2.x=fmaf(o2.x,6.0f,m2.x); f2.y=fmaf(o2.y,6.0f,m2.y); f2.z=fmaf(o2.z,6.0f,m2.z); f2.w=fmaf(o2.w,6.0f,m2.w);

    float* outb = out + (size_t)b * 3 * WH;
    const fvec4 y0 = aff4(f0, f1, f2, r00, r01, r02, t0);
    const fvec4 y1 = aff4(f0, f1, f2, r10, r11, r12, t1);
    const fvec4 y2 = aff4(f0, f1, f2, r20, r21, r22, t2);
    __builtin_nontemporal_store(y0, (fvec4*)(outb + 0*WH + p));
    __builtin_nontemporal_store(y1, (fvec4*)(outb + 1*WH + p));
    __builtin_nontemporal_store(y2, (fvec4*)(outb + 2*WH + p));
}

extern "C" void kernel_launch(void* const* d_in, const int* in_sizes, int n_in,
                              void* d_out, int out_size, void* d_ws, size_t ws_size,
                              hipStream_t stream) {
    const float* Off   = (const float*)d_in[0];
    const float* P     = (const float*)d_in[1];
    const float* att   = (const float*)d_in[2];
    const float* meanp = (const float*)d_in[3];
    const int*   uv    = (const int*)d_in[4];
    float* out = (float*)d_out;
    float* RT  = (float*)d_ws;   // 12 floats per batch

    const int B = in_sizes[0] / (3 * WH);

    solve_kernel<<<B, 64, 0, stream>>>(Off, P, att, meanp, uv, RT);

    dim3 grid(WH / (256 * 4), B);
    apply_kernel<<<grid, 256, 0, stream>>>(Off, meanp, RT, out);
}